// Round 12
// baseline (122.860 us; speedup 1.0000x reference)
//
#include <hip/hip_runtime.h>
#include <cmath>

// Problem constants (fixed by setup_inputs)
constexpr int NN = 2;       // batch
constexpr int LL = 2048;    // sequence
constexpr int HH = 8;       // heads
constexpr int EE = 32;      // feature dim == value dim
constexpr int CC = 32;      // chunk length -> grid 1024 = 4 blocks/CU
constexpr int NCH = LL / CC;       // 64 chunks per (n,h)
constexpr int NB  = NN * HH * NCH; // 1024 blocks
constexpr int BWD = 10;     // softmax bandwidth
constexpr float EPSF = 1e-6f;
// ws record per chunk: S1[32*32], k1[32], S2[32*32], k2[32] (floats)
constexpr int REC  = 2 * (EE * EE + EE);   // 2112 floats = 528 float4
constexpr int REC4 = REC / 4;              // 528
constexpr int OFF_S1 = 0, OFF_K1 = 1024, OFF_S2 = 1056, OFF_K2 = 2080;
constexpr int SK = EE + 4;   // 36: float4/float2-aligned row stride (144 B)

// key_lengths cancels (normalization over E after a per-row constant mult).
// Factorization: Qf=elu1(q), Kf=elu1(k): Q1n.K1n = qi1*ki1*(Qf.Kf),
// Q2n.K2n = qi2*ki2*sum((qf*kf)^2).
//
// Occupancy math (R12): waves/CU = (grid/256 CUs) x (threads/64)
//   = 4 blocks/CU x 8 waves = 32 waves/CU (HW max) -- needs VGPR <= 64.
//   R8 measured 44 VGPR at 512 threads with MORE per-thread state -> fits.
//   Do NOT force min-waves via launch_bounds 2nd arg (R7: 187 MB spill).

__device__ __forceinline__ float elu1(float x) {
    return x > 0.f ? x + 1.f : __expf(x);   // elu(x)+1
}

// ---------------- Kernel 1: stage = chunk sums + banded softmax --------------
// One block per (n,h,chunk); 512 threads = 16-lane cluster/row, float2/lane.
// K,V staged once serve the ws state-matmul AND the band (out = W1*SV).
// Per-(e,d) ws accumulation order (j ascending) unchanged -> ws bits same.
__global__ __launch_bounds__(512) void stage_kernel(
    const float* __restrict__ Qin, const float* __restrict__ Kin,
    const float* __restrict__ Vin, const float* __restrict__ W1,
    float* __restrict__ ws, float* __restrict__ out)
{
    __shared__ float Kr [CC + 9][SK];      // raw K, rows l0-9 .. l0+31
    __shared__ float Vs [CC + 9][SK];      // V, same window
    __shared__ float K1n[CC][SK];          // normalized K branch 1
    __shared__ float K2n[CC][SK];          // normalized K branch 2

    const int b  = blockIdx.x;
    const int c  = b & (NCH - 1);
    const int nh = b >> 6;
    const int h  = nh & 7;
    const int n  = nh >> 3;
    const int l0 = c * CC;
    const int t  = threadIdx.x;
    const int lane = t & 31;
    const int grp  = t >> 5;       // 0..15

    // cluster identity (band + phase 2 share it: r == e)
    const int r   = t >> 4;        // 0..31
    const int sub = t & 15;
    const int d0  = sub * 2;
    const int l   = l0 + r;

    // band Q pair early (latency hides under staging)
    const float2 q2 = *(const float2*)&Qin[((n * LL + l) * HH + h) * EE + d0];

    // ---------------- staging + feature map + normalize ----------------------
    for (int rr = grp; rr < CC; rr += 16) {
        const int ll = l0 + rr;
        const int base = ((n * LL + ll) * HH + h) * EE + lane;
        const float k = Kin[base];
        const float v = Vin[base];
        const float f1 = elu1(k);
        const float f2 = f1 * f1;
        float s1 = f1, s2 = f2;
        #pragma unroll
        for (int m = 1; m < 32; m <<= 1) {
            s1 += __shfl_xor(s1, m, 32);
            s2 += __shfl_xor(s2, m, 32);
        }
        K1n[rr][lane] = f1 / s1;
        K2n[rr][lane] = f2 / s2;
        Kr [9 + rr][lane] = k;
        Vs [9 + rr][lane] = v;
    }
    // previous 9 rows of raw K,V for the band window
    if (t < 9 * 32) {
        const int rr = t >> 5, ln = t & 31;
        const int ll = l0 - 9 + rr;
        float kv = 0.f, vv = 0.f;
        if (ll >= 0) {
            const int base = ((n * LL + ll) * HH + h) * EE + ln;
            kv = Kin[base];
            vv = Vin[base];
        }
        Kr[rr][ln] = kv;
        Vs[rr][ln] = vv;
    }
    __syncthreads();

    // ---------------- band: online softmax, 16-lane cluster f2 ---------------
    {
        const float temp = 0.17677669529663687f;   // 1/sqrt(32)
        float mx = -INFINITY, den = 0.f;
        float sv0 = 0.f, sv1 = 0.f;
        #pragma unroll
        for (int jj = 0; jj < BWD; ++jj) {
            const int j = l - (BWD - 1) + jj;   // global key row
            if (j >= 0) {                        // uniform per 16-lane row group
                const float2 k2 = *(const float2*)&Kr[r + jj][d0];
                float p = q2.x * k2.x + q2.y * k2.y;
                p += __shfl_xor(p, 1, 16); p += __shfl_xor(p, 2, 16);
                p += __shfl_xor(p, 4, 16); p += __shfl_xor(p, 8, 16);
                const float s  = p * temp;
                const float mn = fmaxf(mx, s);
                const float c1 = __expf(mx - mn);   // 0 on first iter
                const float c2 = __expf(s - mn);
                const float2 v2 = *(const float2*)&Vs[r + jj][d0];
                den = den * c1 + c2;
                sv0 = sv0 * c1 + c2 * v2.x;
                sv1 = sv1 * c1 + c2 * v2.y;
                mx = mn;
            }
        }
        const float inv = 1.f / den;
        const float2 w1 = *(const float2*)&W1[h * EE + d0];
        float2 o;
        o.x = w1.x * sv0 * inv;
        o.y = w1.y * sv1 * inv;
        // full-coverage store: erases d_out poison everywhere
        *(float2*)&out[((n * LL + l) * HH + h) * EE + d0] = o;
    }

    // ---------------- phase 2: chunk state sums -> ws (identical order) ------
    {
        const int e = r;                 // 0..31
        float a1x = 0.f, a1y = 0.f, a2x = 0.f, a2y = 0.f;
        float ks1 = 0.f, ks2 = 0.f;
        for (int j = 0; j < CC; ++j) {
            const float k1 = K1n[j][e];     // multicast, free
            const float k2 = K2n[j][e];
            const float2 v = *(const float2*)&Vs[9 + j][d0];
            ks1 += k1; ks2 += k2;
            a1x += k1 * v.x; a1y += k1 * v.y;
            a2x += k2 * v.x; a2y += k2 * v.y;
        }
        float* wb = ws + (size_t)b * REC;
        *(float2*)&wb[OFF_S1 + e * EE + d0] = make_float2(a1x, a1y);
        *(float2*)&wb[OFF_S2 + e * EE + d0] = make_float2(a2x, a2y);
        if (sub == 0) {
            wb[OFF_K1 + e] = ks1;
            wb[OFF_K2 + e] = ks2;
        }
    }
}

// ---------------- Kernel 2: exclusive prefix over chunks per (n,h) -----------
// register scan (R5-proven), NCH=64 as two 32-deep passes.
__global__ __launch_bounds__(192) void prefix_kernel(float* __restrict__ ws)
{
    const int g = blockIdx.x / 11;
    const int e = (blockIdx.x % 11) * 192 + threadIdx.x;   // 0..2111
    float* base = ws + (size_t)g * NCH * REC + e;
    float run = 0.f;
    {
        float v[32];
        #pragma unroll
        for (int c = 0; c < 32; ++c) v[c] = base[(size_t)c * REC];
        #pragma unroll
        for (int c = 0; c < 32; ++c) {
            const float x = v[c];
            base[(size_t)c * REC] = run;
            run += x;
        }
    }
    {
        float v[32];
        #pragma unroll
        for (int c = 0; c < 32; ++c) v[c] = base[(size_t)(32 + c) * REC];
        #pragma unroll
        for (int c = 0; c < 32; ++c) {
            const float x = v[c];
            base[(size_t)(32 + c) * REC] = run;
            run += x;
        }
    }
}

// ---------------- Kernel 3: linear branches, out += --------------------------
// One block per (n,h,chunk); 512 threads = 16-lane cluster/row, float2/lane;
// ONE barrier. Reads only its own ws record + out from stage (proven RMW).
__global__ __launch_bounds__(512) void linear_kernel(
    const float* __restrict__ Qin, const float* __restrict__ Kin,
    const float* __restrict__ Vin,
    const float* __restrict__ W2, const float* __restrict__ W3,
    const float* __restrict__ ws, float* __restrict__ out)
{
    __shared__ float Kf [CC][SK];          // elu1(K)
    __shared__ float Vs [CC][SK];
    __shared__ float Qf [CC][SK];          // elu1(Q), multicast reads in e-loop
    __shared__ float ki1[CC], ki2[CC], qi1[CC], qi2[CC];
    __shared__ __align__(16) float sp[REC];   // own prefix record (ws layout)

    const int b  = blockIdx.x;
    const int c  = b & (NCH - 1);
    const int nh = b >> 6;
    const int h  = nh & 7;
    const int n  = nh >> 3;
    const int l0 = c * CC;
    const int t  = threadIdx.x;
    const int lane = t & 31;
    const int grp  = t >> 5;       // 0..15

    const int r   = t >> 4;        // row 0..31
    const int sub = t & 15;
    const int d0  = sub * 2;
    const int l   = l0 + r;
    const int ob  = ((n * LL + l) * HH + h) * EE + d0;

    // early global loads: own prefix record, Q pair, current out (band part)
    const float4* wbv = (const float4*)(ws + (size_t)b * REC);
    float4 s0 = {0.f, 0.f, 0.f, 0.f};
    if (t < REC4) s0 = wbv[t];                      // 512 of 528
    float4 s1 = {0.f, 0.f, 0.f, 0.f};
    if (t < REC4 - 512) s1 = wbv[512 + t];          // last 16
    const float2 q2    = *(const float2*)&Qin[ob];
    const float2 oprev = *(const float2*)&out[ob];

    // publish prefix record now — own-slot writes, readers sync below
    if (t < REC4) ((float4*)sp)[t] = s0;
    if (t < REC4 - 512) ((float4*)sp)[512 + t] = s1;

    // ---------------- staging + feature maps + row sums ----------------------
    for (int rr = grp; rr < CC; rr += 16) {
        const int ll = l0 + rr;
        const int base = ((n * LL + ll) * HH + h) * EE + lane;
        const float k = Kin[base];
        const float v = Vin[base];
        const float q = Qin[base];
        const float fk = elu1(k), fk2 = fk * fk;
        const float fq = elu1(q), fq2 = fq * fq;
        float sk1 = fk, sk2 = fk2, sq1 = fq, sq2 = fq2;
        #pragma unroll
        for (int m = 1; m < 32; m <<= 1) {
            sk1 += __shfl_xor(sk1, m, 32);
            sk2 += __shfl_xor(sk2, m, 32);
            sq1 += __shfl_xor(sq1, m, 32);
            sq2 += __shfl_xor(sq2, m, 32);
        }
        Kf[rr][lane] = fk;
        Qf[rr][lane] = fq;
        Vs[rr][lane] = v;
        if (lane == 0) {
            ki1[rr] = 1.f / sk1; ki2[rr] = 1.f / sk2;
            qi1[rr] = 1.f / sq1; qi2[rr] = 1.f / sq2;
        }
    }
    __syncthreads();   // the ONLY barrier

    const float* S1p = sp + OFF_S1;
    const float* S2p = sp + OFF_S2;
    const float* k1p = sp + OFF_K1;
    const float* k2p = sp + OFF_K2;

    const float qi1v = qi1[r];     // multicast
    const float qi2v = qi2[r];
    float2 qf2;                    // elu1(q) from registers
    qf2.x = elu1(q2.x); qf2.y = elu1(q2.y);

    float a1x = 0.f, a1y = 0.f, a2x = 0.f, a2y = 0.f;
    float dp1 = 0.f, dp2 = 0.f;

    // prefix contribution: a1 += Qf[e]*S1p[e][:], a2 += Qf[e]^2*S2p[e][:]
    #pragma unroll 4
    for (int e = 0; e < EE; ++e) {
        const float tq  = Qf[r][e];            // multicast
        const float tq2 = tq * tq;
        dp1 += tq  * k1p[e];
        dp2 += tq2 * k2p[e];
        const float2 sa = *(const float2*)&S1p[e * EE + d0];
        const float2 ta = *(const float2*)&S2p[e * EE + d0];
        a1x += tq  * sa.x; a1y += tq  * sa.y;
        a2x += tq2 * ta.x; a2y += tq2 * ta.y;
    }

    // intra-chunk causal: one Kf read serves both branches
    for (int j = 0; j <= r; ++j) {
        const float2 kf = *(const float2*)&Kf[j][d0];
        const float t0 = qf2.x * kf.x, t1 = qf2.y * kf.y;
        float u1 = t0 + t1;
        float u2 = t0 * t0 + t1 * t1;
        u1 += __shfl_xor(u1, 1, 16); u1 += __shfl_xor(u1, 2, 16);
        u1 += __shfl_xor(u1, 4, 16); u1 += __shfl_xor(u1, 8, 16);
        u2 += __shfl_xor(u2, 1, 16); u2 += __shfl_xor(u2, 2, 16);
        u2 += __shfl_xor(u2, 4, 16); u2 += __shfl_xor(u2, 8, 16);
        const float p1 = u1 * ki1[j];          // multicast
        const float p2 = u2 * ki2[j];
        dp1 += p1;
        dp2 += p2;
        const float2 va = *(const float2*)&Vs[j][d0];
        a1x += p1 * va.x; a1y += p1 * va.y;
        a2x += p2 * va.x; a2y += p2 * va.y;
    }

    const float z1 = qi1v / (qi1v * dp1 + EPSF);
    const float z2 = qi2v / (qi2v * dp2 + EPSF);
    const float2 w2 = *(const float2*)&W2[h * EE + d0];
    const float2 w3 = *(const float2*)&W3[h * EE + d0];
    float2 o;
    o.x = oprev.x + w2.x * a1x * z1 + w3.x * a2x * z2;
    o.y = oprev.y + w2.y * a1y * z1 + w3.y * a2y * z2;
    *(float2*)&out[ob] = o;
}

extern "C" void kernel_launch(void* const* d_in, const int* in_sizes, int n_in,
                              void* d_out, int out_size, void* d_ws, size_t ws_size,
                              hipStream_t stream)
{
    const float* Q  = (const float*)d_in[0];
    const float* K  = (const float*)d_in[1];
    const float* V  = (const float*)d_in[2];
    // d_in[3] = key_lengths: cancels mathematically (normalization over E)
    const float* W1 = (const float*)d_in[4];
    const float* W2 = (const float*)d_in[5];
    const float* W3 = (const float*)d_in[6];
    float* out = (float*)d_out;
    float* ws  = (float*)d_ws;   // uses NB*REC*4 = ~8.7 MB of scratch

    stage_kernel  <<<NB,           512, 0, stream>>>(Q, K, V, W1, ws, out);
    prefix_kernel <<<NN * HH * 11, 192, 0, stream>>>(ws);
    linear_kernel <<<NB,           512, 0, stream>>>(Q, K, V, W2, W3, ws, out);
}

// Round 13
// 107.391 us; speedup vs baseline: 1.1440x; 1.1440x over previous
//
#include <hip/hip_runtime.h>
#include <cmath>

// Problem constants (fixed by setup_inputs)
constexpr int NN = 2;       // batch
constexpr int LL = 2048;    // sequence
constexpr int HH = 8;       // heads
constexpr int EE = 32;      // feature dim == value dim
constexpr int CC = 32;      // chunk length (4 blocks/CU, half triangle work)
constexpr int NCH = LL / CC;       // 64 chunks per (n,h)
constexpr int NB  = NN * HH * NCH; // 1024 blocks
constexpr int BWD = 10;     // softmax bandwidth
constexpr float EPSF = 1e-6f;
// ws record per chunk: S1[32*32], k1[32], S2[32*32], k2[32] (floats)
constexpr int REC  = 2 * (EE * EE + EE);   // 2112 floats = 528 float4
constexpr int REC4 = REC / 4;              // 528
constexpr int OFF_S1 = 0, OFF_K1 = 1024, OFF_S2 = 1056, OFF_K2 = 2080;
constexpr int SK = EE + 4;   // 36: float4-aligned row stride (144 B, 16B-aligned)

// key_lengths cancels (normalized over E after a per-row constant multiply).
// Factorization: with Qf=elu1(q), Kf=elu1(k): Q1n.K1n = qi1*ki1*(Qf.Kf),
// Q2n.K2n = qi2*ki2*sum((qf*kf)^2) — one Kf array serves both branches.
//
// R13 = exact revert to R10, the measured optimum (106.7 us). Plateau
// evidence: R11 (fewer insts/barriers) = 107.7, R12 (wider blocks) = 122.9.
// Remaining time = ~46 us harness ws-poison floor (256 MB fill at 80% HBM
// peak inside every replay) + 3 ordered latency-bound dispatches whose
// serial-scan dependency cannot be collapsed on this harness (coop launch
// fails silently [R2]; cross-kernel ws fan-in diverges post-timing [R3]).

__device__ __forceinline__ float elu1(float x) {
    return x > 0.f ? x + 1.f : __expf(x);   // elu(x)+1
}

// ---------------- Kernel 1: per-chunk state sums -> ws -----------------------
// one block per (n,h,chunk); 256 threads, CC=32
__global__ __launch_bounds__(256) void chunksum_kernel(
    const float* __restrict__ Kin, const float* __restrict__ Vin,
    float* __restrict__ ws)
{
    __shared__ float K1n[CC][SK];
    __shared__ float K2n[CC][SK];
    __shared__ float Vs [CC][SK];

    const int b  = blockIdx.x;
    const int c  = b & (NCH - 1);
    const int nh = b >> 6;
    const int t  = threadIdx.x;
    const int lane = t & 31;
    const int grp  = t >> 5;    // 0..7

    for (int r = grp; r < CC; r += 8) {
        const int l = c * CC + r;
        const int base = ((nh >> 3) * LL + l) * HH * EE + (nh & 7) * EE + lane;
        const float k = Kin[base];
        const float v = Vin[base];
        const float f1 = elu1(k);
        const float f2 = f1 * f1;
        float s1 = f1, s2 = f2;
        #pragma unroll
        for (int m = 1; m < 32; m <<= 1) {
            s1 += __shfl_xor(s1, m, 32);
            s2 += __shfl_xor(s2, m, 32);
        }
        K1n[r][lane] = f1 / s1;
        K2n[r][lane] = f2 / s2;
        Vs [r][lane] = v;
    }
    __syncthreads();

    const int e  = t >> 3;          // 0..31
    const int d0 = (t & 7) * 4;     // 0..28
    float4 a1 = {0.f, 0.f, 0.f, 0.f};
    float4 a2 = {0.f, 0.f, 0.f, 0.f};
    float ks1 = 0.f, ks2 = 0.f;
    for (int j = 0; j < CC; ++j) {
        const float k1 = K1n[j][e];     // multicast, free
        const float k2 = K2n[j][e];
        const float4 v = *(const float4*)&Vs[j][d0];
        ks1 += k1; ks2 += k2;
        a1.x += k1 * v.x; a1.y += k1 * v.y; a1.z += k1 * v.z; a1.w += k1 * v.w;
        a2.x += k2 * v.x; a2.y += k2 * v.y; a2.z += k2 * v.z; a2.w += k2 * v.w;
    }
    float* wb = ws + (size_t)b * REC;
    *(float4*)&wb[OFF_S1 + e * EE + d0] = a1;
    *(float4*)&wb[OFF_S2 + e * EE + d0] = a2;
    if ((t & 7) == 0) {
        wb[OFF_K1 + e] = ks1;
        wb[OFF_K2 + e] = ks2;
    }
}

// ---------------- Kernel 2: exclusive prefix over chunks per (n,h) -----------
// register scan (R5-proven), NCH=64 as two 32-deep passes.
__global__ __launch_bounds__(192) void prefix_kernel(float* __restrict__ ws)
{
    const int g = blockIdx.x / 11;
    const int e = (blockIdx.x % 11) * 192 + threadIdx.x;   // 0..2111
    float* base = ws + (size_t)g * NCH * REC + e;
    float run = 0.f;
    {
        float v[32];
        #pragma unroll
        for (int c = 0; c < 32; ++c) v[c] = base[(size_t)c * REC];
        #pragma unroll
        for (int c = 0; c < 32; ++c) {
            const float x = v[c];
            base[(size_t)c * REC] = run;
            run += x;
        }
    }
    {
        float v[32];
        #pragma unroll
        for (int c = 0; c < 32; ++c) v[c] = base[(size_t)(32 + c) * REC];
        #pragma unroll
        for (int c = 0; c < 32; ++c) {
            const float x = v[c];
            base[(size_t)(32 + c) * REC] = run;
            run += x;
        }
    }
}

// ---------------- Kernel 3: band + linear + single store ---------------------
// one block per (n,h,chunk); 256 threads. Band: 8-lane cluster per row,
// ALIGNED stride-36 float4 Kr/Vs reads + online softmax (5 DS insts per 8
// scores). Band output stays in registers (same (r,d-quad) mapping as
// Phase C). Linear: factorized single-Kf cluster dots. Reads ONLY its own
// ws record (proven dataflow).
__global__ __launch_bounds__(256) void fused_kernel(
    const float* __restrict__ Qin, const float* __restrict__ Kin,
    const float* __restrict__ Vin,
    const float* __restrict__ W1, const float* __restrict__ W2,
    const float* __restrict__ W3, const float* __restrict__ ws,
    float* __restrict__ out)
{
    __shared__ float Kf [CC][SK];          // elu1(K), f4 rows
    __shared__ float Vs [CC + 9][SK];      // rows l0-9 .. l0+31
    __shared__ float Qf [CC][SK];          // elu1(Q), scalar-bcast reads (e-loop)
    __shared__ float ki1[CC], ki2[CC], qi1[CC], qi2[CC];
    // raw-K (band) and prefix state (linear): disjoint lifetimes
    __shared__ __align__(16) union {
        float kr[(CC + 9) * SK];           // 1476 floats, f4-aligned rows
        float sp[REC];                     // 2112 floats, ws-record layout
    } U;

    const int b  = blockIdx.x;
    const int c  = b & (NCH - 1);
    const int nh = b >> 6;
    const int h  = nh & 7;
    const int n  = nh >> 3;
    const int l0 = c * CC;
    const int t  = threadIdx.x;
    const int lane = t & 31;
    const int grp  = t >> 5;       // 0..7

    // own exclusive-prefix record -> registers early (hides under A/B)
    const float4* wbv = (const float4*)(ws + (size_t)b * REC);
    const float4 s0 = wbv[t];
    const float4 s1 = wbv[256 + t];
    float4 s2 = {0.f, 0.f, 0.f, 0.f};
    if (t < REC4 - 512) s2 = wbv[512 + t];          // last 16

    // ---------------- Phase A: staging + feature maps + row sums -------------
    for (int r = grp; r < CC; r += 8) {
        const int l = l0 + r;
        const int base = ((n * LL + l) * HH + h) * EE + lane;
        const float k = Kin[base];
        const float v = Vin[base];
        const float q = Qin[base];
        const float fk = elu1(k), fk2 = fk * fk;
        const float fq = elu1(q), fq2 = fq * fq;
        float sk1 = fk, sk2 = fk2, sq1 = fq, sq2 = fq2;
        #pragma unroll
        for (int m = 1; m < 32; m <<= 1) {
            sk1 += __shfl_xor(sk1, m, 32);
            sk2 += __shfl_xor(sk2, m, 32);
            sq1 += __shfl_xor(sq1, m, 32);
            sq2 += __shfl_xor(sq2, m, 32);
        }
        Kf[r][lane] = fk;
        Qf[r][lane] = fq;
        Vs[9 + r][lane] = v;
        U.kr[(9 + r) * SK + lane] = k;
        if (lane == 0) {
            ki1[r] = 1.f / sk1; ki2[r] = 1.f / sk2;
            qi1[r] = 1.f / sq1; qi2[r] = 1.f / sq2;
        }
    }
    // previous 9 rows of raw K,V for the band window
    for (int idx = t; idx < 9 * 32; idx += 256) {
        const int rr = idx >> 5, ln = idx & 31;
        const int l = l0 - 9 + rr;
        float kv = 0.f, vv = 0.f;
        if (l >= 0) {
            const int base = ((n * LL + l) * HH + h) * EE + ln;
            kv = Kin[base];
            vv = Vin[base];
        }
        U.kr[rr * SK + ln] = kv;
        Vs[rr][ln] = vv;
    }

    // cluster identity for phases B and C
    const int r   = t >> 3;        // row 0..31
    const int sub = t & 7;
    const int d0  = sub * 4;
    const int l   = l0 + r;

    // raw Q quad in registers (serves band dot AND, via elu1, Phase C)
    const float4 q4 = *(const float4*)&Qin[((n * LL + l) * HH + h) * EE + d0];
    __syncthreads();

    // ---------------- Phase B: banded ONLINE softmax, cluster f4 -------------
    float bnd[4];
    {
        const float temp = 0.17677669529663687f;   // 1/sqrt(32)
        float mx = -INFINITY, den = 0.f;
        float sv0 = 0.f, sv1 = 0.f, sv2 = 0.f, sv3 = 0.f;
        #pragma unroll
        for (int jj = 0; jj < BWD; ++jj) {
            const int j = l - (BWD - 1) + jj;   // global key row
            if (j >= 0) {                        // uniform per 8-lane row group
                const float4 k4 = *(const float4*)&U.kr[(r + jj) * SK + d0];
                float p = q4.x*k4.x + q4.y*k4.y + q4.z*k4.z + q4.w*k4.w;
                p += __shfl_xor(p, 1, 8); p += __shfl_xor(p, 2, 8); p += __shfl_xor(p, 4, 8);
                const float s  = p * temp;
                const float mn = fmaxf(mx, s);
                const float c1 = __expf(mx - mn);   // 0 on first iter
                const float c2 = __expf(s - mn);
                const float4 v4 = *(const float4*)&Vs[r + jj][d0];
                den = den * c1 + c2;
                sv0 = sv0 * c1 + c2 * v4.x;
                sv1 = sv1 * c1 + c2 * v4.y;
                sv2 = sv2 * c1 + c2 * v4.z;
                sv3 = sv3 * c1 + c2 * v4.w;
                mx = mn;
            }
        }
        const float inv = 1.f / den;
        const float4 w1 = *(const float4*)&W1[h * EE + d0];
        bnd[0] = w1.x * sv0 * inv; bnd[1] = w1.y * sv1 * inv;
        bnd[2] = w1.z * sv2 * inv; bnd[3] = w1.w * sv3 * inv;
    }
    __syncthreads();   // all reads of U.kr done

    // publish own prefix record into U.sp (same layout as ws record)
    ((float4*)U.sp)[t]       = s0;
    ((float4*)U.sp)[256 + t] = s1;
    if (t < REC4 - 512) ((float4*)U.sp)[512 + t] = s2;
    __syncthreads();

    const float* S1p = U.sp + OFF_S1;
    const float* S2p = U.sp + OFF_S2;
    const float* k1p = U.sp + OFF_K1;
    const float* k2p = U.sp + OFF_K2;

    // ---------------- Phase C: 8-lane cluster per row, factorized ------------
    const float qi1v = qi1[r];     // multicast
    const float qi2v = qi2[r];
    float4 qf4;                    // elu1(q) from registers (no LDS read)
    qf4.x = elu1(q4.x); qf4.y = elu1(q4.y);
    qf4.z = elu1(q4.z); qf4.w = elu1(q4.w);

    float a1[4] = {0.f, 0.f, 0.f, 0.f};   // unscaled (x qi at end)
    float a2[4] = {0.f, 0.f, 0.f, 0.f};
    float dp1 = 0.f, dp2 = 0.f;

    // prefix contribution: a1 += Qf[e]*S1p[e][:], a2 += Qf[e]^2*S2p[e][:]
    #pragma unroll 4
    for (int e = 0; e < EE; ++e) {
        const float tq  = Qf[r][e];            // multicast
        const float tq2 = tq * tq;
        dp1 += tq  * k1p[e];
        dp2 += tq2 * k2p[e];
        const float4 sa = *(const float4*)&S1p[e * EE + d0];
        const float4 ta = *(const float4*)&S2p[e * EE + d0];
        a1[0] += tq  * sa.x; a1[1] += tq  * sa.y; a1[2] += tq  * sa.z; a1[3] += tq  * sa.w;
        a2[0] += tq2 * ta.x; a2[1] += tq2 * ta.y; a2[2] += tq2 * ta.z; a2[3] += tq2 * ta.w;
    }

    // intra-chunk causal: one Kf read serves both branches
    for (int j = 0; j <= r; ++j) {
        const float4 kf = *(const float4*)&Kf[j][d0];
        const float t0 = qf4.x * kf.x, t1 = qf4.y * kf.y;
        const float t2 = qf4.z * kf.z, t3 = qf4.w * kf.w;
        float u1 = (t0 + t1) + (t2 + t3);
        float u2 = ((t0 * t0 + t1 * t1) + (t2 * t2 + t3 * t3));
        u1 += __shfl_xor(u1, 1, 8); u1 += __shfl_xor(u1, 2, 8); u1 += __shfl_xor(u1, 4, 8);
        u2 += __shfl_xor(u2, 1, 8); u2 += __shfl_xor(u2, 2, 8); u2 += __shfl_xor(u2, 4, 8);
        const float p1 = u1 * ki1[j];          // multicast
        const float p2 = u2 * ki2[j];
        dp1 += p1;
        dp2 += p2;
        const float4 va = *(const float4*)&Vs[9 + j][d0];
        a1[0] += p1 * va.x; a1[1] += p1 * va.y; a1[2] += p1 * va.z; a1[3] += p1 * va.w;
        a2[0] += p2 * va.x; a2[1] += p2 * va.y; a2[2] += p2 * va.z; a2[3] += p2 * va.w;
    }

    const float z1 = qi1v / (qi1v * dp1 + EPSF);
    const float z2 = qi2v / (qi2v * dp2 + EPSF);
    const float4 w2 = *(const float4*)&W2[h * EE + d0];
    const float4 w3 = *(const float4*)&W3[h * EE + d0];
    float4 o;
    o.x = bnd[0] + w2.x * a1[0] * z1 + w3.x * a2[0] * z2;
    o.y = bnd[1] + w2.y * a1[1] * z1 + w3.y * a2[1] * z2;
    o.z = bnd[2] + w2.z * a1[2] * z1 + w3.z * a2[2] * z2;
    o.w = bnd[3] + w2.w * a1[3] * z1 + w3.w * a2[3] * z2;
    *(float4*)&out[((n * LL + l) * HH + h) * EE + d0] = o;
}

extern "C" void kernel_launch(void* const* d_in, const int* in_sizes, int n_in,
                              void* d_out, int out_size, void* d_ws, size_t ws_size,
                              hipStream_t stream)
{
    const float* Q  = (const float*)d_in[0];
    const float* K  = (const float*)d_in[1];
    const float* V  = (const float*)d_in[2];
    // d_in[3] = key_lengths: cancels mathematically (normalization over E)
    const float* W1 = (const float*)d_in[4];
    const float* W2 = (const float*)d_in[5];
    const float* W3 = (const float*)d_in[6];
    float* out = (float*)d_out;
    float* ws  = (float*)d_ws;   // uses NB*REC*4 = ~8.7 MB of scratch

    chunksum_kernel<<<NB,           256, 0, stream>>>(K, V, ws);
    prefix_kernel  <<<NN * HH * 11, 192, 0, stream>>>(ws);
    fused_kernel   <<<NB,           256, 0, stream>>>(Q, K, V, W1, W2, W3, ws, out);
}